// Round 3
// baseline (79.931 us; speedup 1.0000x reference)
//
#include <hip/hip_runtime.h>
#include <hip/hip_bf16.h>

// Problem constants (from reference setup_inputs)
#define T1 4095     // existing stack entries
#define TT 4096     // T1 + 1
#define B  64
#define M  128
#define BM (B * M)                // 8192
#define ROW4 (BM / 4)             // 2048 float4 per row
#define SCAN_THREADS 256
#define EPT (TT / SCAN_THREADS)   // 16 elements per thread in scan
#define RPB 16                    // rows per fuse block
#define NBLK (TT / RPB)           // 256 fuse blocks (1 per CU)
#define ITS (ROW4 / 256)          // 8 float4 windows per row per thread

typedef float f32x4 __attribute__((ext_vector_type(4)));

// Kernel 1: per batch b (one block per b):
//   sn[i] = relu(s[i] - relu(u - suffix_s[i])), sn[T1] = d
//   coeff[i] = min(sn[i], relu(1 - suffix_sn[i]))
// sn -> output layout [TT,B]; coeff -> TRANSPOSED [B,TT] for coalesced reuse.
__global__ __launch_bounds__(SCAN_THREADS) void scan_kernel(
    const float* __restrict__ s,    // [T1, B]
    const float* __restrict__ d,    // [B]
    const float* __restrict__ u,    // [B]
    float* __restrict__ sn_out,     // [TT, B]  (output 1)
    float* __restrict__ coeffT)     // [B, TT]  (workspace, transposed)
{
    const int b = blockIdx.x;
    const int t = threadIdx.x;
    __shared__ float sh[SCAN_THREADS];

    const int base = t * EPT;
    float sv[EPT];
    float sum = 0.f;
#pragma unroll
    for (int k = 0; k < EPT; ++k) {
        int i = base + k;
        float val = (i < T1) ? s[(size_t)i * B + b] : 0.f;
        sv[k] = val;
        sum += val;
    }
    const float mysum = sum;
    sh[t] = sum;
    __syncthreads();
#pragma unroll
    for (int dstep = 1; dstep < SCAN_THREADS; dstep <<= 1) {
        float add = (t + dstep < SCAN_THREADS) ? sh[t + dstep] : 0.f;
        __syncthreads();
        sh[t] += add;
        __syncthreads();
    }
    float suffix = sh[t] - mysum;   // sum over threads > t

    const float ub = u[b];
    float tot = suffix;
    float snv[EPT];
#pragma unroll
    for (int k = EPT - 1; k >= 0; --k) {
        float sval = sv[k];
        snv[k] = fmaxf(sval - fmaxf(ub - tot, 0.f), 0.f);
        tot += sval;
    }
    if (t == SCAN_THREADS - 1) snv[EPT - 1] = d[b];  // element T1: sn = d

    float sum2 = 0.f;
#pragma unroll
    for (int k = 0; k < EPT; ++k) sum2 += snv[k];
    __syncthreads();           // protect sh reuse
    sh[t] = sum2;
    __syncthreads();
#pragma unroll
    for (int dstep = 1; dstep < SCAN_THREADS; dstep <<= 1) {
        float add = (t + dstep < SCAN_THREADS) ? sh[t + dstep] : 0.f;
        __syncthreads();
        sh[t] += add;
        __syncthreads();
    }
    float suffix2 = sh[t] - sum2;

    float tot2 = suffix2;
    float cv[EPT];
#pragma unroll
    for (int k = EPT - 1; k >= 0; --k) {
        float snval = snv[k];
        cv[k] = fminf(snval, fmaxf(1.f - tot2, 0.f));
        tot2 += snval;
    }
#pragma unroll
    for (int k = 0; k < EPT; ++k)
        sn_out[(size_t)(base + k) * B + b] = snv[k];
    f32x4* cT4 = (f32x4*)(coeffT + (size_t)b * TT + base);
#pragma unroll
    for (int q = 0; q < EPT / 4; ++q) {
        f32x4 cc = { cv[4*q+0], cv[4*q+1], cv[4*q+2], cv[4*q+3] };
        cT4[q] = cc;
    }
}

// Kernel 2: fused Vn copy + coeff-weighted partial reduction.
// 256 blocks (1/CU); block g streams rows [16g, 16g+16) CONTIGUOUSLY
// (512 KB read + 512 KB write linear). Coeffs in LDS, broadcast reads.
__global__ __launch_bounds__(256) void fuse_kernel(
    const float* __restrict__ V,        // [T1, B, M]
    const float* __restrict__ v,        // [B, M]
    const float* __restrict__ coeffT,   // [B, TT]
    float* __restrict__ Vn,             // [TT, B, M] (output 0)
    float* __restrict__ partials)       // [NBLK, BM]
{
    const int g = blockIdx.x;
    const int tid = threadIdx.x;
    const int i0 = g * RPB;
    __shared__ float cf[B * RPB];       // cf[b*RPB + k]

    // Stage this block's 64x16 coefficient tile (4 KB).
    {
        const int b = tid >> 2, k4 = tid & 3;
        f32x4 cc = *(const f32x4*)(coeffT + (size_t)b * TT + i0 + k4 * 4);
        ((f32x4*)cf)[tid] = cc;         // float4 index b*4+k4 == tid
    }
    __syncthreads();

    f32x4 acc[ITS];
#pragma unroll
    for (int it = 0; it < ITS; ++it) acc[it] = (f32x4){0.f, 0.f, 0.f, 0.f};

    const f32x4* Vp  = (const f32x4*)V;
    const f32x4* vp  = (const f32x4*)v;
    f32x4*       Vnp = (f32x4*)Vn;

#pragma unroll 4
    for (int k = 0; k < RPB; ++k) {
        const int row = i0 + k;
        const size_t base4 = (size_t)row * ROW4;
        if (row != T1) {
#pragma unroll
            for (int it = 0; it < ITS; ++it) {
                const int p4 = it * 256 + tid;
                f32x4 val = __builtin_nontemporal_load(&Vp[base4 + p4]);
                __builtin_nontemporal_store(val, &Vnp[base4 + p4]);
                acc[it] += cf[(p4 >> 5) * RPB + k] * val;
            }
        } else {
#pragma unroll
            for (int it = 0; it < ITS; ++it) {
                const int p4 = it * 256 + tid;
                f32x4 val = vp[p4];
                __builtin_nontemporal_store(val, &Vnp[base4 + p4]);
                acc[it] += cf[(p4 >> 5) * RPB + k] * val;
            }
        }
    }
#pragma unroll
    for (int it = 0; it < ITS; ++it)
        __builtin_nontemporal_store(acc[it],
            &((f32x4*)partials)[(size_t)g * ROW4 + it * 256 + tid]);
}

// Kernel 3: deterministic two-level reduction of partials -> r.
// 64 blocks x 256 threads; 8 chunk-groups x 32 float4 outputs per block.
__global__ __launch_bounds__(256) void reduce_kernel(
    const float* __restrict__ partials,  // [NBLK, BM]
    float* __restrict__ r)               // [B, M] (output 2)
{
    const int blk = blockIdx.x;          // 0..63
    const int tid = threadIdx.x;
    const int grp = tid >> 5;            // 0..7
    const int lane = tid & 31;
    const int out4 = blk * 32 + lane;    // float4 output index 0..2047

    f32x4 acc = {0.f, 0.f, 0.f, 0.f};
#pragma unroll 8
    for (int c = grp; c < NBLK; c += 8)
        acc += __builtin_nontemporal_load(
            &((const f32x4*)partials)[(size_t)c * ROW4 + out4]);

    __shared__ f32x4 sh[256];
    sh[tid] = acc;
    __syncthreads();
    if (tid < 128) sh[tid] += sh[tid + 128];
    __syncthreads();
    if (tid < 64) sh[tid] += sh[tid + 64];
    __syncthreads();
    if (tid < 32) {
        f32x4 res = sh[tid] + sh[tid + 32];
        ((f32x4*)r)[out4] = res;
    }
}

extern "C" void kernel_launch(void* const* d_in, const int* in_sizes, int n_in,
                              void* d_out, int out_size, void* d_ws, size_t ws_size,
                              hipStream_t stream) {
    const float* V = (const float*)d_in[0];   // [T1,B,M]
    const float* s = (const float*)d_in[1];   // [T1,B,1]
    const float* d = (const float*)d_in[2];   // [B,1]
    const float* u = (const float*)d_in[3];   // [B,1]
    const float* v = (const float*)d_in[4];   // [B,M]

    float* out = (float*)d_out;
    float* Vn = out;                                   // TT*B*M
    float* sn = out + (size_t)TT * BM;                 // TT*B
    float* r  = sn + (size_t)TT * B;                   // B*M

    float* coeffT   = (float*)d_ws;                    // B*TT floats (1 MB)
    float* partials = coeffT + (size_t)B * TT;         // NBLK*BM floats (8 MB)

    scan_kernel<<<B, SCAN_THREADS, 0, stream>>>(s, d, u, sn, coeffT);
    fuse_kernel<<<NBLK, 256, 0, stream>>>(V, v, coeffT, Vn, partials);
    reduce_kernel<<<64, 256, 0, stream>>>(partials, r);
}

// Round 4
// 78.487 us; speedup vs baseline: 1.0184x; 1.0184x over previous
//
#include <hip/hip_runtime.h>
#include <hip/hip_bf16.h>

// Problem constants (from reference setup_inputs)
#define T1 4095     // existing stack entries
#define TT 4096     // T1 + 1
#define B  64
#define M  128
#define BM (B * M)                // 8192
#define ROW4 (BM / 4)             // 2048 float4 per row
#define SCAN_THREADS 256
#define EPT (TT / SCAN_THREADS)   // 16 elements per thread in scan
#define FUSE_BLOCKS 1024
#define RGRP 128                  // row-groups (threads-per-sweep / ROW4)
#define SWEEPS (TT / RGRP)        // 32 iterations per thread

typedef float f32x4 __attribute__((ext_vector_type(4)));

// Kernel 1: per batch b (one block per b):
//   sn[i] = relu(s[i] - relu(u - suffix_s[i])), sn[T1] = d
//   coeff[i] = min(sn[i], relu(1 - suffix_sn[i]))
// Both written in natural [TT,B] layout.
__global__ __launch_bounds__(SCAN_THREADS) void scan_kernel(
    const float* __restrict__ s,    // [T1, B]
    const float* __restrict__ d,    // [B]
    const float* __restrict__ u,    // [B]
    float* __restrict__ sn_out,     // [TT, B]  (output 1)
    float* __restrict__ coeff)      // [TT, B]  (workspace)
{
    const int b = blockIdx.x;
    const int t = threadIdx.x;
    __shared__ float sh[SCAN_THREADS];

    const int base = t * EPT;
    float sv[EPT];
    float sum = 0.f;
#pragma unroll
    for (int k = 0; k < EPT; ++k) {
        int i = base + k;
        float val = (i < T1) ? s[(size_t)i * B + b] : 0.f;
        sv[k] = val;
        sum += val;
    }
    const float mysum = sum;
    sh[t] = sum;
    __syncthreads();
#pragma unroll
    for (int dstep = 1; dstep < SCAN_THREADS; dstep <<= 1) {
        float add = (t + dstep < SCAN_THREADS) ? sh[t + dstep] : 0.f;
        __syncthreads();
        sh[t] += add;
        __syncthreads();
    }
    float suffix = sh[t] - mysum;   // sum over threads > t

    const float ub = u[b];
    float tot = suffix;
    float snv[EPT];
#pragma unroll
    for (int k = EPT - 1; k >= 0; --k) {
        float sval = sv[k];
        snv[k] = fmaxf(sval - fmaxf(ub - tot, 0.f), 0.f);
        tot += sval;
    }
    if (t == SCAN_THREADS - 1) snv[EPT - 1] = d[b];  // element T1: sn = d

    float sum2 = 0.f;
#pragma unroll
    for (int k = 0; k < EPT; ++k) sum2 += snv[k];
    __syncthreads();           // protect sh reuse
    sh[t] = sum2;
    __syncthreads();
#pragma unroll
    for (int dstep = 1; dstep < SCAN_THREADS; dstep <<= 1) {
        float add = (t + dstep < SCAN_THREADS) ? sh[t + dstep] : 0.f;
        __syncthreads();
        sh[t] += add;
        __syncthreads();
    }
    float suffix2 = sh[t] - sum2;

    float tot2 = suffix2;
#pragma unroll
    for (int k = EPT - 1; k >= 0; --k) {
        float snval = snv[k];
        float c = fminf(snval, fmaxf(1.f - tot2, 0.f));
        tot2 += snval;
        sn_out[(size_t)(base + k) * B + b] = snval;
        coeff[(size_t)(base + k) * B + b] = c;
    }
}

// Kernel 2: fused Vn copy + coeff-weighted partial reduction.
// Grid-stride dense sweep (fill-kernel shaped): 1024 blocks x 256 thr =
// 262144 threads = 128 rows' worth. Thread keeps fixed column bm4 and
// row-group r0; iteration t covers rows [128t, 128t+128) DENSELY.
__global__ __launch_bounds__(256) void fuse_kernel(
    const float* __restrict__ V,        // [T1, B, M]
    const float* __restrict__ v,        // [B, M]
    const float* __restrict__ coeff,    // [TT, B]
    float* __restrict__ Vn,             // [TT, B, M] (output 0)
    float* __restrict__ partials)       // [RGRP, BM]
{
    const int gt  = blockIdx.x * 256 + threadIdx.x;   // 0..262143
    const int bm4 = gt & (ROW4 - 1);                  // fixed column (float4)
    const int r0  = gt >> 11;                         // 0..127
    const int b   = bm4 >> 5;                         // batch of this column

    const f32x4* Vp  = (const f32x4*)V;
    f32x4*       Vnp = (f32x4*)Vn;

    f32x4 acc = {0.f, 0.f, 0.f, 0.f};
#pragma unroll 8
    for (int t = 0; t < SWEEPS - 1; ++t) {
        const int i = r0 + t * RGRP;
        const size_t idx = (size_t)i * ROW4 + bm4;
        f32x4 val = __builtin_nontemporal_load(&Vp[idx]);
        __builtin_nontemporal_store(val, &Vnp[idx]);
        acc += coeff[(size_t)i * B + b] * val;
    }
    {   // last sweep: i == T1 only for r0 == 127 (V[T1] does not exist)
        const int i = r0 + (SWEEPS - 1) * RGRP;
        const size_t idx = (size_t)i * ROW4 + bm4;
        f32x4 val;
        if (i != T1) val = __builtin_nontemporal_load(&Vp[idx]);
        else         val = ((const f32x4*)v)[bm4];
        __builtin_nontemporal_store(val, &Vnp[idx]);
        acc += coeff[(size_t)i * B + b] * val;
    }
    ((f32x4*)partials)[(size_t)r0 * ROW4 + bm4] = acc;
}

// Kernel 3: deterministic reduction of partials -> r.
// 32 blocks x 1024 threads; block owns 64 consecutive float4 outputs
// (1 KB fully-coalesced loads), 16 row-groups reduced via LDS tree.
__global__ __launch_bounds__(1024) void reduce_kernel(
    const float* __restrict__ partials,  // [RGRP, BM]
    float* __restrict__ r)               // [B, M] (output 2)
{
    const int tid  = threadIdx.x;
    const int out4 = blockIdx.x * 64 + (tid & 63);   // 0..2047
    const int grp  = tid >> 6;                       // 0..15

    f32x4 acc = {0.f, 0.f, 0.f, 0.f};
#pragma unroll
    for (int k = 0; k < RGRP / 16; ++k)              // 8 rows per thread
        acc += ((const f32x4*)partials)[(size_t)(grp + 16 * k) * ROW4 + out4];

    __shared__ f32x4 sh[1024];
    sh[tid] = acc;
    __syncthreads();
    if (tid < 512) sh[tid] += sh[tid + 512];
    __syncthreads();
    if (tid < 256) sh[tid] += sh[tid + 256];
    __syncthreads();
    if (tid < 128) sh[tid] += sh[tid + 128];
    __syncthreads();
    if (tid < 64) ((f32x4*)r)[out4] = sh[tid] + sh[tid + 64];
}

extern "C" void kernel_launch(void* const* d_in, const int* in_sizes, int n_in,
                              void* d_out, int out_size, void* d_ws, size_t ws_size,
                              hipStream_t stream) {
    const float* V = (const float*)d_in[0];   // [T1,B,M]
    const float* s = (const float*)d_in[1];   // [T1,B,1]
    const float* d = (const float*)d_in[2];   // [B,1]
    const float* u = (const float*)d_in[3];   // [B,1]
    const float* v = (const float*)d_in[4];   // [B,M]

    float* out = (float*)d_out;
    float* Vn = out;                                   // TT*B*M
    float* sn = out + (size_t)TT * BM;                 // TT*B
    float* r  = sn + (size_t)TT * B;                   // B*M

    float* coeff    = (float*)d_ws;                    // TT*B floats (1 MB)
    float* partials = coeff + (size_t)TT * B;          // RGRP*BM floats (4 MB)

    scan_kernel<<<B, SCAN_THREADS, 0, stream>>>(s, d, u, sn, coeff);
    fuse_kernel<<<FUSE_BLOCKS, 256, 0, stream>>>(V, v, coeff, Vn, partials);
    reduce_kernel<<<32, 1024, 0, stream>>>(partials, r);
}